// Round 11
// baseline (35.614 us; speedup 1.0000x reference)
//
#include <hip/hip_runtime.h>

#define B_TOT 16384
#define F_DIM 512
#define T_DIM 256
#define N_DIM 256
#define NBLK  2048
#define GRPS  64      // level-1 groups
#define GSZ   32      // blocks per group (GRPS*GSZ == NBLK)

__device__ __forceinline__ float wave_sum(float v) {
#pragma unroll
    for (int o = 32; o; o >>= 1) v += __shfl_xor(v, o, 64);
    return v;
}
__device__ __forceinline__ float wave_prod(float v) {
#pragma unroll
    for (int o = 32; o; o >>= 1) v *= __shfl_xor(v, o, 64);
    return v;
}
// logp of the chosen logit: chosen - lse(chosen,other) == -log(1+exp(other-chosen))
__device__ __forceinline__ float pick_lp(float chosen, float other) {
    return -__logf(1.f + __expf(other - chosen));
}

// Round-10 main loop (dense lane mapping, best measured) + fused final
// reduction via a HIERARCHICAL ticket: 64 level-1 counters x 32 RMWs run in
// parallel (~0.3us) + 64 level-2 RMWs (~0.6us), vs round 6's single counter
// whose 2048 serialized RMWs cost ~20us. Publication protocol = round 6's
// validated scheme: relaxed agent-scope atomic stores, manual vmcnt(0)
// release, relaxed agent-scope atomic loads; NO cache-maintenance ops.
// All barriers top-level; non-last blocks exit block-uniformly.
__global__ __launch_bounds__(256, 4) void setcrit_fused(
    const float* __restrict__ pred_class,
    const float* __restrict__ pred_v,
    const float* __restrict__ targets,
    float* __restrict__ partial,
    unsigned int* __restrict__ ctr,   // ctr[0]=level2, ctr[1+g]=level1 group g
    float* __restrict__ out)
{
    __shared__ float s_predv[4][N_DIM];   // private slice per wave
    __shared__ float s_fin[4][4];
    __shared__ float s_red[4];
    __shared__ unsigned int s_last;

    const int tid = threadIdx.x;
    const int l   = tid & 63;
    const int w   = tid >> 6;
    const unsigned long long lt = (1ull << l) - 1ull;
    const int wave_id = blockIdx.x * 4 + w;   // 8192 waves, 2 rows each

    float acc_pick = 0.f, acc_dsq = 0.f, acc_multi = 0.f;
    int   acc_tc = 0;

#pragma unroll
    for (int i = 0; i < 2; ++i) {
        const int b = i * (NBLK * 4) + wave_id;
        const float* lgp = pred_class + (size_t)b * (2 * F_DIM);
        const float* pvp = pred_v     + (size_t)b * N_DIM;
        const float* tgp = targets    + (size_t)b * T_DIM;

        // ---- dense coalesced row loads (16B/8B lane stride) ----
        float4 g0 = *(const float4*)(lgp + 4 * l);          // f = 2l, 2l+1
        float4 g1 = *(const float4*)(lgp + 256 + 4 * l);    // f = 128+2l, 129+2l
        float4 g2 = *(const float4*)(lgp + 512 + 4 * l);    // f = 256+2l, 257+2l
        float4 g3 = *(const float4*)(lgp + 768 + 4 * l);    // f = 384+2l, 385+2l
        float4 pv = *(const float4*)(pvp + 4 * l);          // n = 4l..4l+3
        float2 t0 = *(const float2*)(tgp + 2 * l);          // t = 2l, 2l+1
        float2 t1 = *(const float2*)(tgp + 128 + 2 * l);    // t = 128+2l, 129+2l

        *(float4*)(&s_predv[w][4 * l]) = pv;                // stage for gather

        // ---- log-softmax picks: f<256 -> logp[1], f>=256 -> logp[0] ----
        float p = 0.f;
        p += pick_lp(g0.y, g0.x);
        p += pick_lp(g0.w, g0.z);
        p += pick_lp(g1.y, g1.x);
        p += pick_lp(g1.w, g1.z);
        p += pick_lp(g2.x, g2.y);
        p += pick_lp(g2.z, g2.w);
        p += pick_lp(g3.x, g3.y);
        p += pick_lp(g3.z, g3.w);
        acc_pick += p;

        // ---- mask + exclusive prefix: halves [0,128) and [128,256) ----
        bool m0 = g0.y > g0.x;   // t = 2l
        bool m1 = g0.w > g0.z;   // t = 2l+1
        bool m2 = g1.y > g1.x;   // t = 128+2l
        bool m3 = g1.w > g1.z;   // t = 129+2l
        unsigned long long b0 = __ballot(m0);
        unsigned long long b1 = __ballot(m1);
        unsigned long long b2 = __ballot(m2);
        unsigned long long b3 = __ballot(m3);

        int e0 = __popcll(b0 & lt) + __popcll(b1 & lt);
        int e1 = e0 + (m0 ? 1 : 0);
        int h  = __popcll(b0) + __popcll(b1);      // total masked in [0,128)
        int e2 = h + __popcll(b2 & lt) + __popcll(b3 & lt);
        int e3 = e2 + (m2 ? 1 : 0);
        acc_tc += h + __popcll(b2) + __popcll(b3);

        // ---- matched gather + squared error (tc==0 rows contribute 0) ----
        float dsq = 0.f, d;
        if (m0) { d = s_predv[w][e0] - t0.x; dsq += d * d; }
        if (m1) { d = s_predv[w][e1] - t0.y; dsq += d * d; }
        if (m2) { d = s_predv[w][e2] - t1.x; dsq += d * d; }
        if (m3) { d = s_predv[w][e3] - t1.y; dsq += d * d; }
        acc_dsq += dsq;

        // ---- product over the row ----
        float prod = wave_prod(pv.x * pv.y * pv.z * pv.w);
        float pm1 = prod - 1.f;
        acc_multi += pm1 * pm1;
    }

    float pickS = wave_sum(acc_pick);
    float dsqS  = wave_sum(acc_dsq);
    if (l == 0) {
        s_fin[w][0] = pickS;
        s_fin[w][1] = acc_multi;
        s_fin[w][2] = dsqS;
        s_fin[w][3] = (float)acc_tc;
    }
    __syncthreads();

    if (tid == 0) {
        float v0 = 0.f, v1 = 0.f, v2 = 0.f, v3 = 0.f;
#pragma unroll
        for (int k = 0; k < 4; ++k) {
            v0 += s_fin[k][0]; v1 += s_fin[k][1];
            v2 += s_fin[k][2]; v3 += s_fin[k][3];
        }
        __hip_atomic_store(&partial[0 * NBLK + blockIdx.x], v0,
                           __ATOMIC_RELAXED, __HIP_MEMORY_SCOPE_AGENT);
        __hip_atomic_store(&partial[1 * NBLK + blockIdx.x], v1,
                           __ATOMIC_RELAXED, __HIP_MEMORY_SCOPE_AGENT);
        __hip_atomic_store(&partial[2 * NBLK + blockIdx.x], v2 * (1.f / (float)T_DIM),
                           __ATOMIC_RELAXED, __HIP_MEMORY_SCOPE_AGENT);
        __hip_atomic_store(&partial[3 * NBLK + blockIdx.x], v3 * (1.f / (float)T_DIM),
                           __ATOMIC_RELAXED, __HIP_MEMORY_SCOPE_AGENT);
        // manual release: partials at the coherence point before any ticket
        asm volatile("s_waitcnt vmcnt(0)" ::: "memory");
        unsigned int last = 0;
        unsigned int t1 = __hip_atomic_fetch_add(&ctr[1 + (blockIdx.x >> 5)], 1u,
                               __ATOMIC_RELAXED, __HIP_MEMORY_SCOPE_AGENT);
        if (t1 == GSZ - 1) {   // this block completed its group
            unsigned int t2 = __hip_atomic_fetch_add(&ctr[0], 1u,
                                   __ATOMIC_RELAXED, __HIP_MEMORY_SCOPE_AGENT);
            last = (t2 == GRPS - 1);
        }
        s_last = last;
    }
    __syncthreads();

    if (!s_last) return;                 // block-uniform exit

    // ---- globally last block: deterministic fixed-order final reduction ----
    float v = 0.f;
#pragma unroll
    for (int i = 0; i < NBLK / 64; ++i)
        v += __hip_atomic_load(&partial[w * NBLK + i * 64 + l],
                               __ATOMIC_RELAXED, __HIP_MEMORY_SCOPE_AGENT);
    v = wave_sum(v);
    if (l == 0) s_red[w] = v;
    __syncthreads();

    if (tid == 0) {
        float loss_label = -s_red[0] / ((float)B_TOT * (float)F_DIM);
        float loss_multi = s_red[1] / (float)B_TOT;
        float loss_true  = s_red[2] / (float)B_TOT;
        float f1         = s_red[3] / (float)B_TOT;
        float r = loss_multi + loss_true;
        out[0] = loss_label + r;
        out[1] = loss_label;
        out[2] = r;
        out[3] = loss_multi;
        out[4] = loss_true;
        out[5] = f1;
    }
}

extern "C" void kernel_launch(void* const* d_in, const int* in_sizes, int n_in,
                              void* d_out, int out_size, void* d_ws, size_t ws_size,
                              hipStream_t stream) {
    const float* pred_class = (const float*)d_in[0];
    const float* pred_v     = (const float*)d_in[1];
    const float* targets    = (const float*)d_in[2];

    float* partial = (float*)d_ws;                         // 4*NBLK floats = 32 KB
    unsigned int* ctr = (unsigned int*)((char*)d_ws + 4 * NBLK * sizeof(float));

    hipMemsetAsync(ctr, 0, (1 + GRPS) * sizeof(unsigned int), stream);
    setcrit_fused<<<NBLK, 256, 0, stream>>>(pred_class, pred_v, targets,
                                            partial, ctr, (float*)d_out);
}

// Round 12
// 21.082 us; speedup vs baseline: 1.6893x; 1.6893x over previous
//
#include <hip/hip_runtime.h>

#define B_TOT 16384
#define F_DIM 512
#define T_DIM 256
#define N_DIM 256
#define NBLK  2048

typedef float f4v __attribute__((ext_vector_type(4)));
typedef float f2v __attribute__((ext_vector_type(2)));

__device__ __forceinline__ float wave_sum(float v) {
#pragma unroll
    for (int o = 32; o; o >>= 1) v += __shfl_xor(v, o, 64);
    return v;
}
__device__ __forceinline__ float wave_prod(float v) {
#pragma unroll
    for (int o = 32; o; o >>= 1) v *= __shfl_xor(v, o, 64);
    return v;
}
// logp of the chosen logit: chosen - lse(chosen,other) == -log(1+exp(other-chosen))
__device__ __forceinline__ float pick_lp(float chosen, float other) {
    return -__logf(1.f + __expf(other - chosen));
}

// Round-10 structure (best measured: 23.5us) + NONTEMPORAL loads: all three
// inputs are single-use streams (pred_v consumed via its LDS copy), so mark
// them nt to cut cache-allocation/eviction pressure behind the stream.
__global__ __launch_bounds__(256, 4) void setcrit_stage1(
    const float* __restrict__ pred_class,
    const float* __restrict__ pred_v,
    const float* __restrict__ targets,
    float* __restrict__ partial)
{
    __shared__ float s_predv[4][N_DIM];   // private slice per wave
    __shared__ float s_fin[4][4];

    const int tid = threadIdx.x;
    const int l   = tid & 63;
    const int w   = tid >> 6;
    const unsigned long long lt = (1ull << l) - 1ull;
    const int wave_id = blockIdx.x * 4 + w;   // 8192 waves, 2 rows each

    float acc_pick = 0.f, acc_dsq = 0.f, acc_multi = 0.f;
    int   acc_tc = 0;

#pragma unroll
    for (int i = 0; i < 2; ++i) {
        const int b = i * (NBLK * 4) + wave_id;
        const float* lgp = pred_class + (size_t)b * (2 * F_DIM);
        const float* pvp = pred_v     + (size_t)b * N_DIM;
        const float* tgp = targets    + (size_t)b * T_DIM;

        // ---- dense coalesced streaming loads (nt: single-use data) ----
        f4v g0 = __builtin_nontemporal_load((const f4v*)(lgp + 4 * l));        // f = 2l, 2l+1
        f4v g1 = __builtin_nontemporal_load((const f4v*)(lgp + 256 + 4 * l));  // f = 128+2l,129+2l
        f4v g2 = __builtin_nontemporal_load((const f4v*)(lgp + 512 + 4 * l));  // f = 256+2l,257+2l
        f4v g3 = __builtin_nontemporal_load((const f4v*)(lgp + 768 + 4 * l));  // f = 384+2l,385+2l
        f4v pv = __builtin_nontemporal_load((const f4v*)(pvp + 4 * l));        // n = 4l..4l+3
        f2v t0 = __builtin_nontemporal_load((const f2v*)(tgp + 2 * l));        // t = 2l, 2l+1
        f2v t1 = __builtin_nontemporal_load((const f2v*)(tgp + 128 + 2 * l));  // t = 128+2l,129+2l

        *(f4v*)(&s_predv[w][4 * l]) = pv;                  // stage for gather

        // ---- log-softmax picks: f<256 -> logp[1], f>=256 -> logp[0] ----
        float p = 0.f;
        p += pick_lp(g0.y, g0.x);
        p += pick_lp(g0.w, g0.z);
        p += pick_lp(g1.y, g1.x);
        p += pick_lp(g1.w, g1.z);
        p += pick_lp(g2.x, g2.y);
        p += pick_lp(g2.z, g2.w);
        p += pick_lp(g3.x, g3.y);
        p += pick_lp(g3.z, g3.w);
        acc_pick += p;

        // ---- mask + exclusive prefix: halves [0,128) and [128,256) ----
        bool m0 = g0.y > g0.x;   // t = 2l
        bool m1 = g0.w > g0.z;   // t = 2l+1
        bool m2 = g1.y > g1.x;   // t = 128+2l
        bool m3 = g1.w > g1.z;   // t = 129+2l
        unsigned long long b0 = __ballot(m0);
        unsigned long long b1 = __ballot(m1);
        unsigned long long b2 = __ballot(m2);
        unsigned long long b3 = __ballot(m3);

        int e0 = __popcll(b0 & lt) + __popcll(b1 & lt);
        int e1 = e0 + (m0 ? 1 : 0);
        int h  = __popcll(b0) + __popcll(b1);      // total masked in [0,128)
        int e2 = h + __popcll(b2 & lt) + __popcll(b3 & lt);
        int e3 = e2 + (m2 ? 1 : 0);
        acc_tc += h + __popcll(b2) + __popcll(b3);

        // ---- matched gather + squared error (tc==0 rows contribute 0) ----
        float dsq = 0.f, d;
        if (m0) { d = s_predv[w][e0] - t0.x; dsq += d * d; }
        if (m1) { d = s_predv[w][e1] - t0.y; dsq += d * d; }
        if (m2) { d = s_predv[w][e2] - t1.x; dsq += d * d; }
        if (m3) { d = s_predv[w][e3] - t1.y; dsq += d * d; }
        acc_dsq += dsq;

        // ---- product over the row ----
        float prod = wave_prod(pv.x * pv.y * pv.z * pv.w);
        float pm1 = prod - 1.f;
        acc_multi += pm1 * pm1;
    }

    float pickS = wave_sum(acc_pick);
    float dsqS  = wave_sum(acc_dsq);
    if (l == 0) {
        s_fin[w][0] = pickS;
        s_fin[w][1] = acc_multi;
        s_fin[w][2] = dsqS;
        s_fin[w][3] = (float)acc_tc;
    }
    __syncthreads();
    if (tid == 0) {
        float v0 = 0.f, v1 = 0.f, v2 = 0.f, v3 = 0.f;
#pragma unroll
        for (int k = 0; k < 4; ++k) {
            v0 += s_fin[k][0]; v1 += s_fin[k][1];
            v2 += s_fin[k][2]; v3 += s_fin[k][3];
        }
        partial[0 * NBLK + blockIdx.x] = v0;
        partial[1 * NBLK + blockIdx.x] = v1;
        partial[2 * NBLK + blockIdx.x] = v2 * (1.f / (float)T_DIM);
        partial[3 * NBLK + blockIdx.x] = v3 * (1.f / (float)T_DIM);
    }
}

// Wave w reduces component w: 32 independent loads/lane, one shuffle tree,
// one barrier, thread 0 composes the 6 outputs.
__global__ __launch_bounds__(256) void setcrit_stage2(
    const float* __restrict__ partial, float* __restrict__ out)
{
    __shared__ float s_red[4];
    const int tid = threadIdx.x;
    const int l   = tid & 63;
    const int w   = tid >> 6;

    float v = 0.f;
#pragma unroll
    for (int i = 0; i < NBLK / 64; ++i)
        v += partial[w * NBLK + i * 64 + l];
    v = wave_sum(v);
    if (l == 0) s_red[w] = v;
    __syncthreads();

    if (tid == 0) {
        float loss_label = -s_red[0] / ((float)B_TOT * (float)F_DIM);
        float loss_multi = s_red[1] / (float)B_TOT;
        float loss_true  = s_red[2] / (float)B_TOT;
        float f1         = s_red[3] / (float)B_TOT;
        float r = loss_multi + loss_true;
        out[0] = loss_label + r;
        out[1] = loss_label;
        out[2] = r;
        out[3] = loss_multi;
        out[4] = loss_true;
        out[5] = f1;
    }
}

extern "C" void kernel_launch(void* const* d_in, const int* in_sizes, int n_in,
                              void* d_out, int out_size, void* d_ws, size_t ws_size,
                              hipStream_t stream) {
    const float* pred_class = (const float*)d_in[0];
    const float* pred_v     = (const float*)d_in[1];
    const float* targets    = (const float*)d_in[2];
    float* partial = (float*)d_ws;  // 4 * NBLK floats = 32 KB

    setcrit_stage1<<<NBLK, 256, 0, stream>>>(pred_class, pred_v, targets, partial);
    setcrit_stage2<<<1, 256, 0, stream>>>(partial, (float*)d_out);
}